// Round 11
// baseline (608.855 us; speedup 1.0000x reference)
//
#include <hip/hip_runtime.h>
#include <stdint.h>

// Problem constants (from reference): x (N,L,D), attention over the sample axis N.
#define NS 256
#define LS 512
#define DS 256
#define HS 8
#define HD 32
#define SCALE 0.17677669529663687f   // hd^-0.5
#define LOG2E 1.4426950408889634f
#define QSCALE (SCALE * LOG2E)       // folded into Q at projection time

typedef __attribute__((ext_vector_type(4))) float f32x4;
typedef __attribute__((ext_vector_type(8))) __bf16 bf16x8;
typedef __attribute__((ext_vector_type(4))) __bf16 bf16x4;
typedef __attribute__((ext_vector_type(8))) unsigned short ushort8;

// fp32 -> bf16 round-to-nearest-even (finite inputs only)
static __device__ __forceinline__ unsigned short f2bf(float f) {
  unsigned int u = __builtin_bit_cast(unsigned int, f);
  u += 0x7fffu + ((u >> 16) & 1u);
  return (unsigned short)(u >> 16);
}

// async global->LDS, 16B per lane. LDS dest is wave-uniform base + lane*16.
static __device__ __forceinline__ void gld16(const void* g, void* l) {
  __builtin_amdgcn_global_load_lds((const __attribute__((address_space(1))) void*)g,
                                   (__attribute__((address_space(3))) void*)l, 16, 0, 0);
}

static __device__ __forceinline__ f32x4 mfma16(bf16x8 a, bf16x8 b, f32x4 c) {
  return __builtin_amdgcn_mfma_f32_16x16x32_bf16(a, b, c, 0, 0, 0);
}

// ---------------- fp32 -> bf16 conversion (vectorized, grid-stride) ----------------
__global__ void k_cvt(const float* __restrict__ in, unsigned short* __restrict__ out, int n) {
  int stride = gridDim.x * blockDim.x;
  for (int i = blockIdx.x * blockDim.x + threadIdx.x; i * 8 < n; i += stride) {
    int b = i * 8;
    float4 a0 = *(const float4*)(in + b);
    float4 a1 = *(const float4*)(in + b + 4);
    ushort8 o;
    o[0] = f2bf(a0.x); o[1] = f2bf(a0.y); o[2] = f2bf(a0.z); o[3] = f2bf(a0.w);
    o[4] = f2bf(a1.x); o[5] = f2bf(a1.y); o[6] = f2bf(a1.z); o[7] = f2bf(a1.w);
    *(ushort8*)(out + b) = o;
  }
}

// ---------------- QKV projection GEMM ----------------
// C[r][e] = sum_d x_row(r)[d] * w_qkv[e][d]; Q part (e<256) pre-scaled by QSCALE.
__global__ __launch_bounds__(256) void k_qkv(const unsigned short* __restrict__ xb,
                                             const unsigned short* __restrict__ wq,
                                             unsigned short* __restrict__ qkv) {
  __shared__ unsigned short As[128 * 64];
  __shared__ unsigned short Bs[128 * 64];
  const int tid = threadIdx.x, lane = tid & 63, wid = tid >> 6;
  const int bid = blockIdx.x;
  const int et = bid % 6, rt = bid / 6;
  const int l = rt >> 1, n0 = (rt & 1) << 7;
  const int wr = wid >> 1, wc = wid & 1;

  f32x4 acc[4][4] = {};
  const int rowA = lane >> 3;
  const int kkA = (lane & 7) * 8;

  for (int kt = 0; kt < 4; ++kt) {
    __syncthreads();
    const int k0 = kt * 64;
    for (int p = 0; p < 4; ++p) {
      const int chunk = p * 4 + wid;
      const int row = chunk * 8 + rowA;
      const unsigned short* gA = xb + (((size_t)(n0 + row)) * LS + l) * DS + k0 + kkA;
      gld16(gA, &As[chunk * 8 * 64]);
      const unsigned short* gB = wq + ((size_t)(et * 128 + row)) * DS + k0 + kkA;
      gld16(gB, &Bs[chunk * 8 * 64]);
    }
    __syncthreads();
    for (int kf = 0; kf < 2; ++kf) {
      const int ko = kf * 32 + (lane >> 4) * 8;
      bf16x8 a[4], b[4];
      for (int m = 0; m < 4; ++m)
        a[m] = *(const bf16x8*)&As[(wr * 64 + m * 16 + (lane & 15)) * 64 + ko];
      for (int nn = 0; nn < 4; ++nn)
        b[nn] = *(const bf16x8*)&Bs[(wc * 64 + nn * 16 + (lane & 15)) * 64 + ko];
      for (int m = 0; m < 4; ++m)
        for (int nn = 0; nn < 4; ++nn)
          acc[m][nn] = mfma16(a[m], b[nn], acc[m][nn]);
    }
  }

  const int rbase = (lane >> 4) * 4, cbase = lane & 15;
  for (int m = 0; m < 4; ++m)
    for (int nn = 0; nn < 4; ++nn) {
      const int e = et * 128 + wc * 64 + nn * 16 + cbase;
      const int which = e >> 8, h = (e >> 5) & 7, d = e & 31;
      const float qs = (which == 0) ? QSCALE : 1.0f;
      const size_t base = (((size_t)which * HS + h) * LS + l) * (NS * HD) + d;
      for (int j = 0; j < 4; ++j) {
        const int n = n0 + wr * 64 + m * 16 + rbase + j;
        qkv[base + (size_t)n * HD] = f2bf(acc[m][nn][j] * qs);
      }
    }
}

// ---------------- attention over the sample axis (single-pass softmax) -----------------
// 2 blocks per (h,l); 4 waves x 32 q-rows. m-outer / key-block-inner: a lane holds ALL
// 64 of its row's scores (s[4][4] f32x4) -> ONE global max (tree + 2 shuffles), one
// independent exp2 pass, one sum. No online rescale, no fsc broadcasts, no mo/ls state.
// Bias enters via the MFMA C-operand (float4 bias load == C/D fragment layout).
__global__ __launch_bounds__(256, 3) void k_attn(const unsigned short* __restrict__ qkv,
                                                 const float* __restrict__ dist,
                                                 unsigned short* __restrict__ att) {
  __shared__ unsigned short Vt[32][NS + 8];   // V^T [d][k]
  __shared__ __bf16 Pl[4][16][68];            // per-wave P [q][k] tile (one key-block)
  const int tid = threadIdx.x, lane = tid & 63, wid = tid >> 6;
  const int bid = blockIdx.x;
  const int h = bid >> 10, l = (bid >> 1) & 511, half = bid & 1;
  const int n0 = half << 7;
  const unsigned short* qb = qkv + (((size_t)0 * HS + h) * LS + l) * (NS * HD);
  const unsigned short* kb = qkv + (((size_t)1 * HS + h) * LS + l) * (NS * HD);
  const unsigned short* vb = qkv + (((size_t)2 * HS + h) * LS + l) * (NS * HD);

  // stage V^T (all 256 k-rows; both half-blocks need all keys)
  {
    const unsigned short* vr = vb + tid * HD;
    for (int c = 0; c < 4; ++c) {
      ushort8 v8 = *(const ushort8*)(vr + c * 8);
      for (int jj = 0; jj < 8; ++jj) Vt[c * 8 + jj][tid] = v8[jj];
    }
  }

  const int fr = lane & 15, g = lane >> 4, fk = g * 8;
  const int wq0 = n0 + wid * 32;
  bf16x8 qf[2];
#pragma unroll
  for (int m = 0; m < 2; ++m)
    qf[m] = *(const bf16x8*)(qb + (size_t)(wq0 + m * 16 + fr) * HD + fk);

  __syncthreads();

#pragma unroll
  for (int m = 0; m < 2; ++m) {
    const int qg = wq0 + m * 16 + fr;       // this lane's q row
    f32x4 s[4][4];

    // QK^T for ALL key-blocks, bias folded in via the C operand
#pragma unroll
    for (int cb = 0; cb < 4; ++cb) {
      const int c0 = cb * 64;
      bf16x8 kfr[4];
#pragma unroll
      for (int nn = 0; nn < 4; ++nn)
        kfr[nn] = *(const bf16x8*)(kb + (size_t)(c0 + nn * 16 + fr) * HD + fk);
#pragma unroll
      for (int nn = 0; nn < 4; ++nn) {
        const float4 bvv = *(const float4*)(dist + (size_t)qg * NS + c0 + nn * 16 + g * 4);
        f32x4 c;
        c[0] = bvv.x * LOG2E; c[1] = bvv.y * LOG2E;
        c[2] = bvv.z * LOG2E; c[3] = bvv.w * LOG2E;
        s[cb][nn] = mfma16(kfr[nn], qf[m], c);
      }
    }

    // global row max: per-lane pairwise tree over 64, then 2 shuffles across g
    float vmax[4];
#pragma unroll
    for (int cb = 0; cb < 4; ++cb) {
      float a0 = fmaxf(fmaxf(s[cb][0][0], s[cb][0][1]), fmaxf(s[cb][0][2], s[cb][0][3]));
      float a1 = fmaxf(fmaxf(s[cb][1][0], s[cb][1][1]), fmaxf(s[cb][1][2], s[cb][1][3]));
      float a2 = fmaxf(fmaxf(s[cb][2][0], s[cb][2][1]), fmaxf(s[cb][2][2], s[cb][2][3]));
      float a3 = fmaxf(fmaxf(s[cb][3][0], s[cb][3][1]), fmaxf(s[cb][3][2], s[cb][3][3]));
      vmax[cb] = fmaxf(fmaxf(a0, a1), fmaxf(a2, a3));
    }
    float mx = fmaxf(fmaxf(vmax[0], vmax[1]), fmaxf(vmax[2], vmax[3]));
    mx = fmaxf(mx, __shfl_xor(mx, 16));
    mx = fmaxf(mx, __shfl_xor(mx, 32));

    // exp2 (independent), pack P per key-block, PV accumulate
    f32x4 o0 = {}, o1 = {};
    float rcb[4];
#pragma unroll
    for (int cb = 0; cb < 4; ++cb) {
      const int c0 = cb * 64;
      float r = 0.f;
#pragma unroll
      for (int nn = 0; nn < 4; ++nn) {
        bf16x4 pk;
#pragma unroll
        for (int j = 0; j < 4; ++j) {
          const float p = __builtin_exp2f(s[cb][nn][j] - mx);
          r += p;
          pk[j] = (__bf16)p;
        }
        *(bf16x4*)&Pl[wid][fr][nn * 16 + g * 4] = pk;   // ds_write_b64
      }
      rcb[cb] = r;
#pragma unroll
      for (int kf = 0; kf < 2; ++kf) {
        const int ko = kf * 32 + fk;
        bf16x8 pa = *(const bf16x8*)&Pl[wid][fr][ko];   // ds_read_b128 (same wave)
        bf16x8 vv0 = *(const bf16x8*)&Vt[fr][c0 + ko];
        bf16x8 vv1 = *(const bf16x8*)&Vt[16 + fr][c0 + ko];
        o0 = mfma16(pa, vv0, o0);
        o1 = mfma16(pa, vv1, o1);
      }
    }
    float rs = (rcb[0] + rcb[1]) + (rcb[2] + rcb[3]);
    rs += __shfl_xor(rs, 16);
    rs += __shfl_xor(rs, 32);
    const float inv = 1.0f / rs;

    // finalize this m: divide by row sum (broadcast per o-row), write [n][l][h*32+d]
#pragma unroll
    for (int j = 0; j < 4; ++j) {
      const float invo = __shfl(inv, g * 4 + j);
      const int n = wq0 + m * 16 + g * 4 + j;
      const size_t ob = ((size_t)n * LS + l) * DS + h * HD;
      att[ob + fr]      = f2bf(o0[j] * invo);
      att[ob + 16 + fr] = f2bf(o1[j] * invo);
    }
  }
}

// ---------------- output projection GEMM (+bias, fp32 out) ----------------
__global__ __launch_bounds__(256) void k_proj(const unsigned short* __restrict__ ab,
                                              const unsigned short* __restrict__ wp,
                                              const float* __restrict__ bp,
                                              float* __restrict__ out) {
  __shared__ unsigned short As[128 * 64];
  __shared__ unsigned short Bs[128 * 64];
  const int tid = threadIdx.x, lane = tid & 63, wid = tid >> 6;
  const int bid = blockIdx.x;
  const int et = bid & 1, rt = bid >> 1;
  const int wr = wid >> 1, wc = wid & 1;

  f32x4 acc[4][4] = {};
  const int rowA = lane >> 3;
  const int kkA = (lane & 7) * 8;

  for (int kt = 0; kt < 4; ++kt) {
    __syncthreads();
    const int k0 = kt * 64;
    for (int p = 0; p < 4; ++p) {
      const int chunk = p * 4 + wid;
      const int row = chunk * 8 + rowA;
      const unsigned short* gA = ab + ((size_t)(rt * 128 + row)) * DS + k0 + kkA;
      gld16(gA, &As[chunk * 8 * 64]);
      const unsigned short* gB = wp + ((size_t)(et * 128 + row)) * DS + k0 + kkA;
      gld16(gB, &Bs[chunk * 8 * 64]);
    }
    __syncthreads();
    for (int kf = 0; kf < 2; ++kf) {
      const int ko = kf * 32 + (lane >> 4) * 8;
      bf16x8 a[4], b[4];
      for (int m = 0; m < 4; ++m)
        a[m] = *(const bf16x8*)&As[(wr * 64 + m * 16 + (lane & 15)) * 64 + ko];
      for (int nn = 0; nn < 4; ++nn)
        b[nn] = *(const bf16x8*)&Bs[(wc * 64 + nn * 16 + (lane & 15)) * 64 + ko];
      for (int m = 0; m < 4; ++m)
        for (int nn = 0; nn < 4; ++nn)
          acc[m][nn] = mfma16(a[m], b[nn], acc[m][nn]);
    }
  }

  const int rbase = (lane >> 4) * 4, cbase = lane & 15;
  for (int m = 0; m < 4; ++m)
    for (int nn = 0; nn < 4; ++nn) {
      const int e = et * 128 + wc * 64 + nn * 16 + cbase;
      const float bv = bp[e];
      for (int j = 0; j < 4; ++j) {
        const size_t mm = (size_t)rt * 128 + wr * 64 + m * 16 + rbase + j;
        out[mm * DS + e] = acc[m][nn][j] + bv;
      }
    }
}

extern "C" void kernel_launch(void* const* d_in, const int* in_sizes, int n_in,
                              void* d_out, int out_size, void* d_ws, size_t ws_size,
                              hipStream_t stream) {
  const float* x     = (const float*)d_in[0];  // (256,512,256)
  const float* dist  = (const float*)d_in[1];  // (256,256)
  const float* wqkv  = (const float*)d_in[2];  // (768,256)
  const float* wproj = (const float*)d_in[3];  // (256,256)
  const float* bproj = (const float*)d_in[4];  // (256,)
  float* out = (float*)d_out;

  // ws layout (ushort elements):
  unsigned short* ws   = (unsigned short*)d_ws;
  unsigned short* xb   = ws;                    // 33,554,432  x as bf16 [n][l][d]
  unsigned short* wqb  = xb + 33554432;         // 196,608     w_qkv bf16
  unsigned short* wpb  = wqb + 196608;          // 65,536      w_proj bf16
  unsigned short* qkvb = wpb + 65536;           // 100,663,296 [3][h][l][n][hd] bf16
  unsigned short* attb = qkvb + 100663296;      // 33,554,432  attn out bf16

  k_cvt<<<8192, 256, 0, stream>>>(x, xb, 33554432);
  k_cvt<<<96, 256, 0, stream>>>(wqkv, wqb, 196608);
  k_cvt<<<32, 256, 0, stream>>>(wproj, wpb, 65536);
  k_qkv<<<6144, 256, 0, stream>>>(xb, wqb, qkvb);
  k_attn<<<8192, 256, 0, stream>>>(qkvb, dist, attb);
  k_proj<<<2048, 256, 0, stream>>>(attb, wpb, bproj, out);
}